// Round 12
// baseline (163.025 us; speedup 1.0000x reference)
//
#include <hip/hip_runtime.h>
#include <hip/hip_bf16.h>
#include <stdint.h>

#define S_LEN 2048
#define D_DIM 128
#define QT 128          // fallback q rows per block
#define KT 64           // fallback kernel tile
#define NT (S_LEN/KT)
#define TKT 32          // main kernel k-tile
#define TNT (S_LEN/TKT) // 64 tiles total; 32 per k-group

typedef float  f32x4  __attribute__((ext_vector_type(4)));
typedef float  f32x16 __attribute__((ext_vector_type(16)));
typedef short  bf16x8 __attribute__((ext_vector_type(8)));
typedef unsigned int uintx4 __attribute__((ext_vector_type(4)));

__device__ __forceinline__ short f2bf(float f) {
    return __builtin_bit_cast(short, __float2bfloat16(f));
}

__device__ __forceinline__ unsigned int pk2(float lo, float hi) {
    unsigned int d;
    asm("v_cvt_pk_bf16_f32 %0, %1, %2" : "=v"(d) : "v"(lo), "v"(hi));
    return d;
}

__device__ __forceinline__ float r2(float x) {
    float m = fmaxf(x, 0.f);
    return m * m;
}

__device__ __forceinline__ void gload_lds16(const short* g, char* l) {
    __builtin_amdgcn_global_load_lds(
        (const __attribute__((address_space(1))) void*)g,
        (__attribute__((address_space(3))) void*)l,
        16, 0, 0);
}

// ---------------------------------------------------------------------------
// Pre-pass 1: K fp32 -> bf16 row-major copy.
// ---------------------------------------------------------------------------
__global__ __launch_bounds__(256)
void convert_k_kernel(const float* __restrict__ kin, short* __restrict__ kbf) {
    const size_t i = ((size_t)blockIdx.x * 256 + threadIdx.x) * 8;
    f32x4 a = *(const f32x4*)(kin + i);
    f32x4 c = *(const f32x4*)(kin + i + 4);
    bf16x8 t;
    t[0]=f2bf(a[0]); t[1]=f2bf(a[1]); t[2]=f2bf(a[2]); t[3]=f2bf(a[3]);
    t[4]=f2bf(c[0]); t[5]=f2bf(c[1]); t[6]=f2bf(c[2]); t[7]=f2bf(c[3]);
    *(bf16x8*)(kbf + i) = t;
}

// ---------------------------------------------------------------------------
// Pre-pass 2: V fp32 [bh][k][d] -> bf16 transposed VT [bh][d][S_LEN].
// ---------------------------------------------------------------------------
__global__ __launch_bounds__(256)
void transpose_v_kernel(const float* __restrict__ vin, short* __restrict__ vt) {
    __shared__ short T[16 * 130];
    const int tid = threadIdx.x;
    const int blk = blockIdx.x;          // 256 = 32 bh * 8 dgroups
    const int bh  = blk >> 3;
    const int d0  = (blk & 7) * 16;
    const float* vb = vin + (size_t)bh * S_LEN * D_DIM;
    short* vtb = vt + (size_t)bh * (size_t)D_DIM * S_LEN;
    const int c4 = tid & 3;
    const int rr = tid >> 2;
    const int dl = tid >> 4;
    const int kc = tid & 15;

    for (int kc0 = 0; kc0 < S_LEN; kc0 += 128) {
        #pragma unroll
        for (int h = 0; h < 2; ++h) {
            const int krow = kc0 + h*64 + rr;
            f32x4 a = *(const f32x4*)(vb + (size_t)krow * D_DIM + d0 + c4*4);
            #pragma unroll
            for (int j = 0; j < 4; ++j)
                T[(c4*4 + j)*130 + h*64 + rr] = f2bf(a[j]);
        }
        __syncthreads();
        int w0 = *(const int*)&T[dl*130 + kc*8 + 0];
        int w1 = *(const int*)&T[dl*130 + kc*8 + 2];
        int w2 = *(const int*)&T[dl*130 + kc*8 + 4];
        int w3 = *(const int*)&T[dl*130 + kc*8 + 6];
        int4 val = make_int4(w0, w1, w2, w3);
        *(int4*)(vtb + (size_t)(d0 + dl) * S_LEN + kc0 + kc*8) = val;
        __syncthreads();
    }
}

// ---------------------------------------------------------------------------
// Main kernel: 256 threads = 2 q-subtiles (32 rows) x 2 k-groups.
// Block covers 64 q-rows; group g owns k-tiles [g*32, g*32+32) (KT=32) with
// a private single-buffered 16KB LDS region -> 32KB/block.  Grid 1024.
// __launch_bounds__(256,3): 170-VGPR budget (live ~138, no spill) ->
// 3 blocks/CU = 12 waves/CU (3/SIMD), independent blocks de-phase pipes.
// Per-wave code: R7-verified KT=32 fragment-major layouts (zero conflicts),
// swapped QK^T, in-register P (cvt_pk + permlane32_swap).
//   K tile (8KB @ GB):       addr = GB + dk*1024 + hi*512 + l31*16
//   V tile (8KB @ GB+8192):  addr = GB+8192 + df*2048 + s_*1024 + hi*512 + l31*16
// Epilogue: group-1 partial O -> LDS (32KB exact), group-0 adds + stores.
// ---------------------------------------------------------------------------
__global__ __launch_bounds__(256, 3)
void relu2_attn_main(const float* __restrict__ q,
                     const short* __restrict__ kbf,
                     const short* __restrict__ vtbf,
                     const float* __restrict__ scale_p,
                     float* __restrict__ out) {
    __shared__ __align__(16) char lds[32768];   // 2 groups x 16KB

    const int tid  = threadIdx.x;
    const int wave = tid >> 6;
    const int lane = tid & 63;
    const int l31  = lane & 31;
    const int hi   = lane >> 5;          // 0/1
    const int wq   = wave & 1;           // q-subtile (32 rows)
    const int grp  = wave >> 1;          // k-group 0/1

    const int bid = blockIdx.x;
    const int bh  = bid & 31;
    const int qt  = bid >> 5;            // 0..31
    const int q0  = qt * 64;

    const float* qb = q    + (size_t)bh * S_LEN * D_DIM;
    const short* kb = kbf  + (size_t)bh * S_LEN * D_DIM;
    const short* vt = vtbf + (size_t)bh * (size_t)D_DIM * S_LEN;
    float*       ob = out  + (size_t)bh * S_LEN * D_DIM;

    const float scale = scale_p[0];

    const int RB = hi*512 + l31*16;      // per-lane LDS read base
    const int GB = grp * 16384;          // group LDS base
    const int tb = grp * 32;             // group's first k-tile

    // ---- staging source offsets (shorts): inverse fragment maps (R7).
    // 8 K-chunks + 8 V-chunks of 1KB per group; chunk ch = p*2 + wq.
    int kOff[4], vOff[4];
    #pragma unroll
    for (int p = 0; p < 4; ++p) {
        const int s = (p*2 + wq)*64 + lane;            // slot in 16B units
        kOff[p] = (s & 31)*128 + (s >> 6)*16 + ((s >> 5) & 1)*8;
        vOff[p] = ((s >> 7)*32 + (s & 31))*2048
                + ((s >> 6) & 1)*16 + ((s >> 5) & 1)*8;
    }

    // ---- Q fragments: lane holds Q[q = q0+wq*32+l31][d = dk*16 + hi*8 + e]
    bf16x8 qa[8];
    {
        const int qrow = q0 + wq*32 + l31;
        const float* qp = qb + (size_t)qrow * D_DIM + hi*8;
        #pragma unroll
        for (int dk = 0; dk < 8; ++dk) {
            f32x4 a = *(const f32x4*)(qp + dk*16);
            f32x4 c = *(const f32x4*)(qp + dk*16 + 4);
            bf16x8 t;
            t[0]=f2bf(a[0]*scale); t[1]=f2bf(a[1]*scale);
            t[2]=f2bf(a[2]*scale); t[3]=f2bf(a[3]*scale);
            t[4]=f2bf(c[0]*scale); t[5]=f2bf(c[1]*scale);
            t[6]=f2bf(c[2]*scale); t[7]=f2bf(c[3]*scale);
            qa[dk] = t;
        }
    }

    f32x16 oacc[4];
    #pragma unroll
    for (int df = 0; df < 4; ++df) oacc[df] = {};

// Stage tile TI into the group's buffer: 8 K + 8 V chunks of 1KB.
#define STAGE(TI) do {                                                        \
    const int k0_ = (TI) * TKT;                                               \
    _Pragma("unroll")                                                         \
    for (int p_ = 0; p_ < 4; ++p_) {                                          \
        const int ch_ = p_*2 + wq;                                            \
        gload_lds16(kb + (size_t)k0_*128 + kOff[p_],                          \
                    lds + GB + ch_*1024);                                     \
        gload_lds16(vt + k0_ + vOff[p_],                                      \
                    lds + GB + 8192 + ch_*1024);                              \
    }                                                                         \
} while (0)

// One KT=32 tile of compute from the group's buffer.
#define TILE_COMPUTE() do {                                                   \
    f32x16 s0 = {};                                                           \
    __builtin_amdgcn_s_setprio(1);                                            \
    _Pragma("unroll")                                                         \
    for (int dk = 0; dk < 8; ++dk) {                                          \
        bf16x8 a = *(const bf16x8*)(lds + GB + RB + (dk<<10));                \
        s0 = __builtin_amdgcn_mfma_f32_32x32x16_bf16(a, qa[dk], s0, 0, 0, 0); \
    }                                                                         \
    __builtin_amdgcn_s_setprio(0);                                            \
    bf16x8 pa[2];                                                             \
    _Pragma("unroll")                                                         \
    for (int t2 = 0; t2 < 2; ++t2) {                                          \
        unsigned int X  = pk2(r2(s0[8*t2+0]), r2(s0[8*t2+1]));                \
        unsigned int Y  = pk2(r2(s0[8*t2+4]), r2(s0[8*t2+5]));                \
        unsigned int X2 = pk2(r2(s0[8*t2+2]), r2(s0[8*t2+3]));                \
        unsigned int Y2 = pk2(r2(s0[8*t2+6]), r2(s0[8*t2+7]));                \
        asm volatile("v_permlane32_swap_b32 %0, %1" : "+v"(X),  "+v"(Y));     \
        asm volatile("v_permlane32_swap_b32 %0, %1" : "+v"(X2), "+v"(Y2));    \
        pa[t2] = __builtin_bit_cast(bf16x8, (uintx4){X, X2, Y, Y2});          \
    }                                                                         \
    __builtin_amdgcn_s_setprio(1);                                            \
    _Pragma("unroll")                                                         \
    for (int s_ = 0; s_ < 2; ++s_) {                                          \
        _Pragma("unroll")                                                     \
        for (int df = 0; df < 4; ++df) {                                      \
            bf16x8 vf = *(const bf16x8*)(lds + GB + 8192 + RB                 \
                                         + (df<<11) + (s_<<10));              \
            oacc[df] = __builtin_amdgcn_mfma_f32_32x32x16_bf16(               \
                           pa[s_], vf, oacc[df], 0, 0, 0);                    \
        }                                                                     \
    }                                                                         \
    __builtin_amdgcn_s_setprio(0);                                            \
} while (0)

    #pragma unroll 1
    for (int t = 0; t < 32; ++t) {
        STAGE(tb + t);
        asm volatile("s_waitcnt vmcnt(0)" ::: "memory");
        __builtin_amdgcn_s_barrier();     // tile resident for both waves
        TILE_COMPUTE();
        __builtin_amdgcn_s_barrier();     // release buffer before next stage
    }

    // ---- epilogue: reduce k-group partials via LDS, group 0 stores.
    // oacc lane layout: O[q = rg*8 + hi*4 + e][d = df*32 + l31]
    float* Fl = (float*)lds;              // [64 q][128 d] f32 = 32 KB
    if (grp == 1) {
        #pragma unroll
        for (int df = 0; df < 4; ++df)
            #pragma unroll
            for (int rg = 0; rg < 4; ++rg)
                #pragma unroll
                for (int e = 0; e < 4; ++e)
                    Fl[(wq*32 + rg*8 + hi*4 + e)*128 + df*32 + l31]
                        = oacc[df][rg*4 + e];
    }
    __syncthreads();
    if (grp == 0) {
        #pragma unroll
        for (int df = 0; df < 4; ++df)
            #pragma unroll
            for (int rg = 0; rg < 4; ++rg)
                #pragma unroll
                for (int e = 0; e < 4; ++e) {
                    const int qr = wq*32 + rg*8 + hi*4 + e;
                    ob[(size_t)(q0 + qr) * D_DIM + df*32 + l31]
                        = oacc[df][rg*4 + e] + Fl[qr*128 + df*32 + l31];
                }
    }
}

// ---------------------------------------------------------------------------
// Fallback (proven R2 kernel) if ws is too small for the bf16 side buffers.
// ---------------------------------------------------------------------------
#define KS 136
#define VS 72
#define PS 72

__global__ __launch_bounds__(256, 2)
void relu2_attn_fallback(const float* __restrict__ q,
                         const float* __restrict__ k,
                         const float* __restrict__ v,
                         const float* __restrict__ scale_p,
                         float* __restrict__ out) {
    __shared__ short Klds[KT][KS];
    __shared__ short VTlds[D_DIM][VS];
    __shared__ short Plds[QT][PS];

    const int tid  = threadIdx.x;
    const int wave = tid >> 6;
    const int lane = tid & 63;
    const int l15  = lane & 15;
    const int lg   = lane >> 4;

    const int bid = blockIdx.x;
    const int bh  = bid & 31;
    const int qt  = bid >> 5;
    const int q0  = qt * QT;

    const float* qb = q + (size_t)bh * S_LEN * D_DIM;
    const float* kb = k + (size_t)bh * S_LEN * D_DIM;
    const float* vb = v + (size_t)bh * S_LEN * D_DIM;
    float*       ob = out + (size_t)bh * S_LEN * D_DIM;

    const float scale = scale_p[0];

    bf16x8 qa[2][4];
    {
        const int qrow = q0 + wave * 32;
        #pragma unroll
        for (int qf = 0; qf < 2; ++qf) {
            const float* qp = qb + (size_t)(qrow + qf*16 + l15) * D_DIM + lg * 8;
            #pragma unroll
            for (int dk = 0; dk < 4; ++dk) {
                f32x4 a = *(const f32x4*)(qp + dk*32);
                f32x4 c = *(const f32x4*)(qp + dk*32 + 4);
                bf16x8 t;
                t[0]=f2bf(a[0]*scale); t[1]=f2bf(a[1]*scale);
                t[2]=f2bf(a[2]*scale); t[3]=f2bf(a[3]*scale);
                t[4]=f2bf(c[0]*scale); t[5]=f2bf(c[1]*scale);
                t[6]=f2bf(c[2]*scale); t[7]=f2bf(c[3]*scale);
                qa[qf][dk] = t;
            }
        }
    }

    const int kr = tid >> 4;
    const int kc = tid & 15;
    const int vd = tid & 127;
    const int vh = (tid >> 7) * 32;

    f32x4 kreg[8];
    float vreg[32];

#define FLOAD_TILE(T) do {                                                    \
    const float* kp_ = kb + (size_t)((T) * KT) * D_DIM;                       \
    _Pragma("unroll")                                                         \
    for (int p = 0; p < 4; ++p) {                                             \
        const float* rp_ = kp_ + (size_t)(p*16 + kr) * D_DIM + kc*8;          \
        kreg[2*p]   = *(const f32x4*)rp_;                                     \
        kreg[2*p+1] = *(const f32x4*)(rp_ + 4);                               \
    }                                                                         \
    const float* vp_ = vb + (size_t)((T) * KT + vh) * D_DIM + vd;             \
    _Pragma("unroll")                                                         \
    for (int j = 0; j < 32; ++j) vreg[j] = vp_[(size_t)j * D_DIM];            \
} while (0)

#define FSTORE_TILE() do {                                                    \
    _Pragma("unroll")                                                         \
    for (int p = 0; p < 4; ++p) {                                             \
        f32x4 a_ = kreg[2*p], b_ = kreg[2*p+1];                               \
        bf16x8 w_;                                                            \
        w_[0]=f2bf(a_[0]); w_[1]=f2bf(a_[1]); w_[2]=f2bf(a_[2]); w_[3]=f2bf(a_[3]); \
        w_[4]=f2bf(b_[0]); w_[5]=f2bf(b_[1]); w_[6]=f2bf(b_[2]); w_[7]=f2bf(b_[3]); \
        *(bf16x8*)&Klds[p*16 + kr][kc*8] = w_;                                \
    }                                                                         \
    _Pragma("unroll")                                                         \
    for (int c = 0; c < 4; ++c) {                                             \
        bf16x8 w_;                                                            \
        w_[0]=f2bf(vreg[c*8+0]); w_[1]=f2bf(vreg[c*8+1]);                     \
        w_[2]=f2bf(vreg[c*8+2]); w_[3]=f2bf(vreg[c*8+3]);                     \
        w_[4]=f2bf(vreg[c*8+4]); w_[5]=f2bf(vreg[c*8+5]);                     \
        w_[6]=f2bf(vreg[c*8+6]); w_[7]=f2bf(vreg[c*8+7]);                     \
        *(bf16x8*)&VTlds[vd][vh + c*8] = w_;                                  \
    }                                                                         \
} while (0)

    f32x4 oacc[2][8];
    #pragma unroll
    for (int i = 0; i < 2; ++i)
        #pragma unroll
        for (int j = 0; j < 8; ++j)
            oacc[i][j] = f32x4{0.f, 0.f, 0.f, 0.f};

    FLOAD_TILE(0);

    for (int t = 0; t < NT; ++t) {
        FSTORE_TILE();
        __syncthreads();
        FLOAD_TILE((t + 1) & (NT - 1));

        f32x4 sacc[2][4];
        #pragma unroll
        for (int qf = 0; qf < 2; ++qf)
            #pragma unroll
            for (int kf = 0; kf < 4; ++kf)
                sacc[qf][kf] = f32x4{0.f, 0.f, 0.f, 0.f};

        #pragma unroll
        for (int dk = 0; dk < 4; ++dk) {
            #pragma unroll
            for (int kf = 0; kf < 4; ++kf) {
                bf16x8 bf = *(const bf16x8*)&Klds[kf*16 + l15][dk*32 + lg*8];
                #pragma unroll
                for (int qf = 0; qf < 2; ++qf)
                    sacc[qf][kf] = __builtin_amdgcn_mfma_f32_16x16x32_bf16(
                        qa[qf][dk], bf, sacc[qf][kf], 0, 0, 0);
            }
        }

        #pragma unroll
        for (int qf = 0; qf < 2; ++qf) {
            #pragma unroll
            for (int kf = 0; kf < 4; ++kf) {
                f32x4 sv = sacc[qf][kf];
                #pragma unroll
                for (int e = 0; e < 4; ++e) {
                    float r = fmaxf(sv[e], 0.f);
                    Plds[wave*32 + qf*16 + lg*4 + e][kf*16 + l15] = f2bf(r * r);
                }
            }
        }

        #pragma unroll
        for (int ks = 0; ks < 2; ++ks) {
            bf16x8 pa[2];
            #pragma unroll
            for (int qf = 0; qf < 2; ++qf)
                pa[qf] = *(const bf16x8*)&Plds[wave*32 + qf*16 + l15][ks*32 + lg*8];
            #pragma unroll
            for (int df = 0; df < 8; ++df) {
                bf16x8 vf = *(const bf16x8*)&VTlds[df*16 + l15][ks*32 + lg*8];
                #pragma unroll
                for (int qf = 0; qf < 2; ++qf)
                    oacc[qf][df] = __builtin_amdgcn_mfma_f32_16x16x32_bf16(
                        pa[qf], vf, oacc[qf][df], 0, 0, 0);
            }
        }
        __syncthreads();
    }

    #pragma unroll
    for (int qf = 0; qf < 2; ++qf) {
        #pragma unroll
        for (int df = 0; df < 8; ++df) {
            f32x4 o = oacc[qf][df];
            const int row = q0 + wave*32 + qf*16 + lg*4;
            float* op = ob + (size_t)row * D_DIM + df*16 + l15;
            op[0*D_DIM] = o[0];
            op[1*D_DIM] = o[1];
            op[2*D_DIM] = o[2];
            op[3*D_DIM] = o[3];
        }
    }
}

extern "C" void kernel_launch(void* const* d_in, const int* in_sizes, int n_in,
                              void* d_out, int out_size, void* d_ws, size_t ws_size,
                              hipStream_t stream) {
    const float* q = (const float*)d_in[0];
    const float* k = (const float*)d_in[1];
    const float* v = (const float*)d_in[2];
    const float* scale = (const float*)d_in[3];
    float* out = (float*)d_out;

    const size_t elems = (size_t)2 * 16 * S_LEN * D_DIM;   // 8.39M per tensor
    const size_t need  = elems * 2 * 2;                    // K + VT bf16 bytes

    if (ws_size >= need) {
        short* kbf = (short*)d_ws;
        short* vtb = (short*)d_ws + elems;
        convert_k_kernel<<<dim3((int)(elems / (256 * 8))), dim3(256), 0, stream>>>(k, kbf);
        transpose_v_kernel<<<dim3(256), dim3(256), 0, stream>>>(v, vtb);
        relu2_attn_main<<<dim3(1024), dim3(256), 0, stream>>>(q, kbf, vtb, scale, out);
    } else {
        relu2_attn_fallback<<<dim3(512), dim3(256), 0, stream>>>(q, k, v, scale, out);
    }
}